// Round 4
// baseline (21457.228 us; speedup 1.0000x reference)
//
#include <hip/hip_runtime.h>
#include <cstddef>
#include <math.h>

// Problem: B=64, S=1024, F=128, H=512, V=64, T=64. f32 in/out.
// R10: 4-chain multiplexed recurrences (32 WGs total).
//  - The 4 batch-groups (16 batches each) are independent recurrences. One WG
//    set (32 WGs, h-sliced as before: 16 h-dims/WG, 1 gate/wave) processes
//    them round-robin: sub-step i stages chain i+1's h (16 far ld16f, tagged
//    u64) while computing chain i (x-part + 64 h-MFMAs + cell). Producer
//    stores land 3-4 sub-steps (~3000cyc) before the consumer's tag check ->
//    first check passes, exchange latency fully hidden (R8/R9 paid it serial
//    every step; that was the 6.4ms floor).
//  - Tagged u64 {packed hi|lo f16, step tag} fire-and-forget stores (R9-
//    proven): no ack, no flags, no post-cell barrier. 2 barriers/sub-step.
//  - Body 4x-unrolled via macro (compile-time chain idx) so c_reg[] and LDS
//    buffer parity are statically indexed (rule #20).
//  - sig loads issued BEFORE the sc0sc1 staging loads: vmcnt retires in
//    issue order, so x-part's waits drain only sig, not the far loads.
//  - Stage-write mapping j=ck+16*c2 (R9 fix): conflict-free b128.
#define NWG 32
#define BPG 16
#define BB  64
#define HH  512
#define TT  64
#define VV  64
#define FF  128
#define SS  1024

typedef _Float16 f16;
typedef _Float16 f16x8 __attribute__((ext_vector_type(8)));
typedef float    f32x4 __attribute__((ext_vector_type(4)));
typedef unsigned int u32;
typedef u32 u32x4 __attribute__((ext_vector_type(4)));
typedef unsigned long long u64;

#define C1 4.8828125e-4f          // 2^-11
#define C2 2.384185791015625e-7f  // 2^-22

__device__ __forceinline__ void split8r(const f32x4& u, const f32x4& v, f16x8& hi, f16x8& lo) {
#pragma unroll
  for (int j = 0; j < 4; ++j) {
    f16 a = (f16)u[j]; hi[j]   = a; lo[j]   = (f16)((u[j] - (float)a) * 2048.0f);
    f16 b = (f16)v[j]; hi[4+j] = b; lo[4+j] = (f16)((v[j] - (float)b) * 2048.0f);
  }
}
__device__ __forceinline__ void split8(const float* __restrict__ p, f16x8& hi, f16x8& lo) {
  f32x4 u = *(const f32x4*)p;
  f32x4 v = *(const f32x4*)(p + 4);
  split8r(u, v, hi, lo);
}
__device__ __forceinline__ float sigmf_(float x) { return 1.0f / (1.0f + expf(-x)); }

// far (coherence-point) accessors
__device__ __forceinline__ f32x4 ld16f(const void* p) {
  f32x4 r;
  asm volatile("global_load_dwordx4 %0, %1, off sc0 sc1" : "=v"(r) : "v"(p) : "memory");
  return r;
}
__device__ __forceinline__ void st8f(u64* p, u64 v) {
  __hip_atomic_store(p, v, __ATOMIC_RELAXED, __HIP_MEMORY_SCOPE_AGENT);
}
__device__ __forceinline__ u64 ld8f(const u64* p) {
  return __hip_atomic_load(p, __ATOMIC_RELAXED, __HIP_MEMORY_SCOPE_AGENT);
}
#define VMWAIT asm volatile("s_waitcnt vmcnt(0)" ::: "memory")

#define MFMA(d, a, b) d = __builtin_amdgcn_mfma_f32_16x16x32_f16(a, b, d, 0, 0, 0)

// ---- tagged h stage: chain tile [16][512] u64 -> LDS hi/lo f16, swizzled ----
// thread (cb,ck) owns 16B-words j = ck+16*c2 of LDS row cb; word j = k [8j,8j+8).
#define STAGE_ISSUE(srcp, cbase)                                              \
  _Pragma("unroll") for (int c2 = 0; c2 < 4; ++c2)                            \
    _Pragma("unroll") for (int u = 0; u < 4; ++u)                             \
      sv[c2*4+u] = ld16f((srcp) + (size_t)((cbase) + cb)*512                  \
                         + (size_t)(ck + 16*c2)*8 + u*2);

// rule #18: after VMWAIT tie results through volatile asm + sched_barrier so
// the register-only tag check can't be hoisted above the wait.
#define STAGE_WAIT(srcp, cbase, tg)                                           \
  for (;;) {                                                                  \
    VMWAIT;                                                                   \
    _Pragma("unroll") for (int u2 = 0; u2 < 16; ++u2)                         \
      asm volatile("" : "+v"(sv[u2]));                                        \
    __builtin_amdgcn_sched_barrier(0);                                        \
    u32 badv[4];                                                              \
    _Pragma("unroll") for (int c2 = 0; c2 < 4; ++c2) {                        \
      badv[c2] = 0;                                                           \
      _Pragma("unroll") for (int u = 0; u < 4; ++u) {                         \
        union { f32x4 f; u32 u4[4]; } U; U.f = sv[c2*4+u];                    \
        badv[c2] |= (U.u4[1] ^ (u32)(tg)) | (U.u4[3] ^ (u32)(tg));            \
      }                                                                       \
    }                                                                         \
    if (__all((badv[0]|badv[1]|badv[2]|badv[3]) == 0)) break;                 \
    __builtin_amdgcn_s_sleep(1);                                              \
    _Pragma("unroll") for (int c2 = 0; c2 < 4; ++c2)                          \
      if (badv[c2]) {                                                         \
        _Pragma("unroll") for (int u = 0; u < 4; ++u)                         \
          sv[c2*4+u] = ld16f((srcp) + (size_t)((cbase) + cb)*512              \
                             + (size_t)(ck + 16*c2)*8 + u*2);                 \
      }                                                                       \
  }

// unpack + swizzled LDS write. byte = (cb*1024 + j*16) ^ ((cb&7)<<4);
// 16 lanes (fixed cb) cover all 8 bank-quads -> 2 lanes/quad = free.
#define STAGE_WRITE(nb)                                                       \
  { const size_t swz = (size_t)((cb & 7) << 4);                               \
    _Pragma("unroll") for (int c2 = 0; c2 < 4; ++c2) {                        \
      u32 hw[4], lw[4];                                                       \
      _Pragma("unroll") for (int u = 0; u < 4; ++u) {                         \
        union { f32x4 f; u32 u4[4]; } U; U.f = sv[c2*4+u];                    \
        hw[u] = (U.u4[0] & 0xffffu) | (U.u4[2] << 16);                        \
        lw[u] = (U.u4[0] >> 16) | (U.u4[2] & 0xffff0000u);                    \
      }                                                                       \
      size_t off = ((size_t)cb*1024 + (size_t)(ck + 16*c2)*16) ^ swz;         \
      *(u32x4*)((char*)&sh_hi[nb][0] + off) = (u32x4){hw[0],hw[1],hw[2],hw[3]}; \
      *(u32x4*)((char*)&sh_lo[nb][0] + off) = (u32x4){lw[0],lw[1],lw[2],lw[3]}; \
    } }

// A-fragment read (row = batch mn, k-slice s), same swizzle as content layout
#define LDA(b, s, ah, al)                                                     \
  { size_t o_ = ((size_t)mn * 1024 + (size_t)(s) * 64 + (size_t)(q8 * 2))     \
                ^ (size_t)((mn & 7) << 4);                                    \
    ah = *(const f16x8*)((const char*)&sh_hi[b][0] + o_);                     \
    al = *(const f16x8*)((const char*)&sh_lo[b][0] + o_); }

#define HPART(b)                                                              \
  _Pragma("unroll") for (int s = 0; s < 16; ++s) {                            \
    f16x8 ah, al; LDA(b, s, ah, al);                                          \
    MFMA(acc0,  ah, whh_h[s]);                                                \
    MFMA(acc1a, al, whh_h[s]);                                                \
    MFMA(acc1b, ah, whh_l[s]);                                                \
    MFMA(acc2,  al, whh_l[s]);                                                \
  }

// C/D layout: col = lane&15 = h-dim, row = (lane>>4)*4 + r = batch
#define GWRITE()                                                              \
  _Pragma("unroll") for (int r = 0; r < 4; ++r)                               \
    gate_buf[w][q*4 + r][mn] = acc0[r] + C1*(acc1a[r] + acc1b[r]) + C2*acc2[r];

// ---- encoder body, compile-time chain CI ----
#define ENC_BODY(CI) {                                                        \
    const u32 tn = (u32)((CI) == 3 ? t + 1 : t);                              \
    /* sig loads FIRST (vmcnt retires in issue order) */                      \
    const float* sb = sig + (size_t)((CI)*16 + mn)*(SS*FF) + (size_t)t*FF;    \
    f32x4 sgl[8];                                                             \
    _Pragma("unroll") for (int s = 0; s < 4; ++s) {                           \
      sgl[2*s]   = *(const f32x4*)(sb + s*32 + q8);                           \
      sgl[2*s+1] = *(const f32x4*)(sb + s*32 + q8 + 4);                       \
    }                                                                         \
    f32x4 sv[16];                                                             \
    STAGE_ISSUE(h16[tn & 1], (((CI)+1)&3) * 16)                               \
    f32x4 acc0 = zero4, acc1a = zero4, acc1b = zero4, acc2 = zero4;           \
    _Pragma("unroll") for (int s = 0; s < 4; ++s) {                           \
      f16x8 ah, al;                                                           \
      split8r(sgl[2*s], sgl[2*s+1], ah, al);                                  \
      MFMA(acc0,  ah, wih_h[s]);  MFMA(acc1a, al, wih_h[s]);                  \
      MFMA(acc1b, ah, wih_l[s]);  MFMA(acc2,  al, wih_l[s]);                  \
    }                                                                         \
    HPART((CI) & 1)                                                           \
    GWRITE()                                                                  \
    __syncthreads();                                                          \
    STAGE_WAIT(h16[tn & 1], (((CI)+1)&3) * 16, tn)                            \
    STAGE_WRITE(((CI)+1) & 1)                                                 \
    {                                                                         \
      float gi = gate_buf[0][cb][ck] + bias_buf[0][ck];                       \
      float gf = gate_buf[1][cb][ck] + bias_buf[1][ck];                       \
      float gg = gate_buf[2][cb][ck] + bias_buf[2][ck];                       \
      float go = gate_buf[3][cb][ck] + bias_buf[3][ck];                       \
      float c  = sigmf_(gf)*c_reg[CI] + sigmf_(gi)*tanhf(gg);                 \
      float h  = sigmf_(go)*tanhf(c);                                         \
      c_reg[CI] = c;                                                          \
      f16 hh = (f16)h;                                                        \
      f16 hl = (f16)((h - (float)hh) * 2048.0f);                              \
      union { f16 h2[2]; u32 u; } pk; pk.h2[0] = hh; pk.h2[1] = hl;           \
      st8f(h16[(t+1) & 1] + (size_t)((CI)*16 + cb)*512 + crow,                \
           (u64)pk.u | ((u64)(u32)(t+1) << 32));                              \
    }                                                                         \
    __syncthreads();                                                          \
  }

// ---- decoder phase-A body, compile-time chain CI ----
#define DEC_BODY(CI) {                                                        \
    const u32 tn = (u32)(SS + ((CI) == 3 ? t + 1 : t));                       \
    f32x4 sv[16];                                                             \
    STAGE_ISSUE(h16[tn & 1], (((CI)+1)&3) * 16)                               \
    u64 iv;                                                                   \
    asm volatile("global_load_dwordx2 %0, %1, off sc0 sc1"                    \
                 : "=v"(iv) : "v"(idx64 + (CI)*16 + cb) : "memory");          \
    f32x4 acc0 = zero4, acc1a = zero4, acc1b = zero4, acc2 = zero4;           \
    HPART((CI) & 1)                                                           \
    GWRITE()                                                                  \
    __syncthreads();                                                          \
    STAGE_WAIT(h16[tn & 1], (((CI)+1)&3) * 16, tn)                            \
    STAGE_WRITE(((CI)+1) & 1)                                                 \
    asm volatile("" : "+v"(iv));                                              \
    __builtin_amdgcn_sched_barrier(0);                                        \
    {                                                                         \
      while ((u32)(iv >> 32) != (u32)(t + 1)) {                               \
        __builtin_amdgcn_s_sleep(1);                                          \
        iv = ld8f(idx64 + (CI)*16 + cb);                                      \
      }                                                                       \
      int ib = (int)(u32)iv;                                                  \
      float gi = gate_buf[0][cb][ck] + bias_buf[0][ck] + dwih_lds[0][ck][ib]; \
      float gf = gate_buf[1][cb][ck] + bias_buf[1][ck] + dwih_lds[1][ck][ib]; \
      float gg = gate_buf[2][cb][ck] + bias_buf[2][ck] + dwih_lds[2][ck][ib]; \
      float go = gate_buf[3][cb][ck] + bias_buf[3][ck] + dwih_lds[3][ck][ib]; \
      float c  = sigmf_(gf)*c_reg[CI] + sigmf_(gi)*tanhf(gg);                 \
      float h  = sigmf_(go)*tanhf(c);                                         \
      c_reg[CI] = c;                                                          \
      f16 hh = (f16)h;                                                        \
      f16 hl = (f16)((h - (float)hh) * 2048.0f);                              \
      union { f16 h2[2]; u32 u; } pk; pk.h2[0] = hh; pk.h2[1] = hl;           \
      st8f(h16[(SS+t+1) & 1] + (size_t)((CI)*16 + cb)*512 + crow,             \
           (u64)pk.u | ((u64)(u32)(SS+t+1) << 32));                           \
      st8f(hfg + (size_t)((CI)*16 + cb)*512 + crow,                           \
           (u64)__float_as_uint(h) | ((u64)(u32)(SS+t+1) << 32));             \
    }                                                                         \
    __syncthreads();                                                          \
  }

__global__ void __launch_bounds__(256, 1) lstm_seq2seq(
    const float* __restrict__ sig,   // [B,S,F]
    const int*   __restrict__ tgt,   // [B,T]
    const float* __restrict__ eWih,  // [2048,128]
    const float* __restrict__ eWhh,  // [2048,512]
    const float* __restrict__ eBih,  // [2048]
    const float* __restrict__ eBhh,  // [2048]
    const float* __restrict__ dWih,  // [2048,64]
    const float* __restrict__ dWhh,  // [2048,512]
    const float* __restrict__ dBih,  // [2048]
    const float* __restrict__ dBhh,  // [2048]
    const float* __restrict__ oW,    // [64,512]
    const float* __restrict__ oB,    // [64]
    float*       __restrict__ out,   // [B,T,V]
    unsigned char* __restrict__ ws)
{
  // ws layout (bytes): [0,512) idx64 u64[64] {idx, tag};
  // [4096, 266240) hfg [64][512] u64 {f32 h, tag};
  // [266240, 790528) h16 2 bufs x [64][512] u64 {packed hi|lo, tag}.
  // Zeroed every launch: tag 0 + value 0 = initial h0 state.
  u64* idx64  = (u64*)ws;
  u64* hfg    = (u64*)(ws + 4096);
  u64* h16[2] = { (u64*)(ws + 266240), (u64*)(ws + 266240 + 262144) };

  const int p    = blockIdx.x;       // h-dim slice [p*16, p*16+16) per gate
  const int tid  = threadIdx.x;
  const int w    = tid >> 6;         // wave = gate (i,f,g,o)
  const int lane = tid & 63;
  const int q    = lane >> 4;
  const int mn   = lane & 15;
  const int q8   = q * 8;
  const int row  = w * HH + p * 16 + mn;  // weight row for this lane's B-frag
  const int cb   = tid >> 4;         // cell/stage: chain-local batch 0..15
  const int ck   = tid & 15;         // cell/stage: dim-slot 0..15
  const int crow = p * 16 + ck;      // cell: h-dim

  __shared__ __attribute__((aligned(16))) f16 sh_hi[2][8192]; // 2x16KB swizzled
  __shared__ __attribute__((aligned(16))) f16 sh_lo[2][8192];
  __shared__ float gate_buf[4][16][20];  // stride 20: quads 2-way max (free)
  __shared__ float bias_buf[4][16];
  __shared__ float dwih_lds[4][16][65];  // decoder W_ih slice, pad 65
  __shared__ __attribute__((aligned(16))) float hrow[2][512];
  __shared__ double psum[2][64];

  // ---- encoder weights: W_hh / W_ih hi/lo fragments in registers ----
  f16x8 whh_h[16], whh_l[16], wih_h[4], wih_l[4];
#pragma unroll
  for (int s = 0; s < 16; ++s)
    split8(eWhh + (size_t)row * HH + s * 32 + q8, whh_h[s], whh_l[s]);
#pragma unroll
  for (int s = 0; s < 4; ++s)
    split8(eWih + (size_t)row * FF + s * 32 + q8, wih_h[s], wih_l[s]);
  if (tid < 64) {
    int g4 = tid >> 4, kl = tid & 15;
    int r = g4 * HH + p * 16 + kl;
    bias_buf[g4][kl] = eBih[r] + eBhh[r];
  }
  if (p == 0 && tid < 64)            // initial idx = target[:,0], tag 1
    st8f(idx64 + tid, (u64)(u32)tgt[(size_t)tid * TT] | (1ull << 32));
  __syncthreads();

  float c_reg[4] = {0.f, 0.f, 0.f, 0.f};
  const f32x4 zero4 = {0.f, 0.f, 0.f, 0.f};

  // prologue: stage chain 0 step 0 (zeros, tag 0) into buf 0
  {
    f32x4 sv[16];
    STAGE_ISSUE(h16[0], 0)
    STAGE_WAIT(h16[0], 0, 0u)
    STAGE_WRITE(0)
  }
  __syncthreads();

  // ================= encoder: 1024 steps x 4 chains =================
  for (int t = 0; t < SS; ++t) {
    ENC_BODY(0)
    ENC_BODY(1)
    ENC_BODY(2)
    ENC_BODY(3)
  }

  // ================= decoder setup =================
#pragma unroll
  for (int s = 0; s < 16; ++s)
    split8(dWhh + (size_t)row * HH + s * 32 + q8, whh_h[s], whh_l[s]);
  if (tid < 64) {
    int g4 = tid >> 4, kl = tid & 15;
    int r = g4 * HH + p * 16 + kl;
    bias_buf[g4][kl] = dBih[r] + dBhh[r];
  }
  for (int i2 = tid; i2 < 4096; i2 += 256) {   // dWih slice -> LDS
    int g4 = i2 >> 10, rem = i2 & 1023, kl = rem >> 6, v = rem & 63;
    dwih_lds[g4][kl][v] = dWih[(size_t)(g4 * HH + p * 16 + kl) * VV + v];
  }
  __syncthreads();

  // ================= decoder: 64 steps x (4 chains + phase B) =================
  for (int t = 0; t < TT; ++t) {
    DEC_BODY(0)
    DEC_BODY(1)
    DEC_BODY(2)
    DEC_BODY(3)
    // ---- phase B: logits/log_softmax/argmax; WG p owns batches 2p, 2p+1 ----
    {
      const u32 tg = (u32)(SS + t + 1);
      {
        int row2 = tid >> 7, kk = tid & 127;
        const u64* hp = hfg + (size_t)(2*p + row2) * 512 + (size_t)kk * 4;
        f32x4 a = ld16f(hp), b2 = ld16f(hp + 2);
        for (;;) {
          VMWAIT;
          asm volatile("" : "+v"(a), "+v"(b2));
          __builtin_amdgcn_sched_barrier(0);
          union { f32x4 f; u32 u4[4]; } A, B2; A.f = a; B2.f = b2;
          u32 bad = (A.u4[1]^tg) | (A.u4[3]^tg) | (B2.u4[1]^tg) | (B2.u4[3]^tg);
          if (__all(bad == 0)) break;
          __builtin_amdgcn_s_sleep(1);
          a = ld16f(hp); b2 = ld16f(hp + 2);
        }
        union { f32x4 f; u32 u4[4]; } A, B2; A.f = a; B2.f = b2;
        hrow[row2][kk*4+0] = __uint_as_float(A.u4[0]);
        hrow[row2][kk*4+1] = __uint_as_float(A.u4[2]);
        hrow[row2][kk*4+2] = __uint_as_float(B2.u4[0]);
        hrow[row2][kk*4+3] = __uint_as_float(B2.u4[2]);
      }
      __syncthreads();
      {
        int bt   = w >> 1;            // batch slot 0/1 -> batch 2p+bt
        int half = w & 1;             // K half
        const float* wr = oW + (size_t)lane * HH + half * 256;
        const float* hr = &hrow[bt][half * 256];
        double acc = 0.0;
#pragma unroll 4
        for (int kc = 0; kc < 64; ++kc) {
          f32x4 hv = *(const f32x4*)(hr + kc * 4);
          f32x4 wv = *(const f32x4*)(wr + kc * 4);
          acc += (double)hv[0]*(double)wv[0] + (double)hv[1]*(double)wv[1]
               + (double)hv[2]*(double)wv[2] + (double)hv[3]*(double)wv[3];
        }
        if (half == 1) psum[bt][lane] = acc;
        __syncthreads();
        if (half == 0) {
          double l = acc + psum[bt][lane] + (double)oB[lane];
          double mx = l; int ai = lane;
#pragma unroll
          for (int o = 32; o > 0; o >>= 1) {
            double om = __shfl_xor(mx, o, 64);
            int    oi = __shfl_xor(ai, o, 64);
            if (om > mx || (om == mx && oi < ai)) { mx = om; ai = oi; }
          }
          double se = exp(l - mx);
#pragma unroll
          for (int o = 32; o > 0; o >>= 1) se += __shfl_xor(se, o, 64);
          double lse = mx + log(se);
          out[((size_t)(2*p + bt) * TT + t) * VV + lane] = (float)(l - lse);
          if (lane == 0)              // argmax -> idx for step t+1, tag t+2
            st8f(idx64 + 2*p + bt, (u64)(u32)ai | ((u64)(u32)(t + 2) << 32));
        }
      }
      __syncthreads();
    }
  }
}

extern "C" void kernel_launch(void* const* d_in, const int* in_sizes, int n_in,
                              void* d_out, int out_size, void* d_ws, size_t ws_size,
                              hipStream_t stream) {
  (void)in_sizes; (void)n_in; (void)out_size; (void)ws_size;
  // zero: idx64 + hfg + h16 (tags must start != any expected tag; h16 tag 0 +
  // value 0 IS the initial h0). ws re-poisoned 0xAA before every timed launch.
  hipMemsetAsync(d_ws, 0, 790528, stream);
  lstm_seq2seq<<<dim3(NWG), dim3(256), 0, stream>>>(
      (const float*)d_in[0],  (const int*)d_in[1],
      (const float*)d_in[2],  (const float*)d_in[3],
      (const float*)d_in[4],  (const float*)d_in[5],
      (const float*)d_in[6],  (const float*)d_in[7],
      (const float*)d_in[8],  (const float*)d_in[9],
      (const float*)d_in[10], (const float*)d_in[11],
      (float*)d_out, (unsigned char*)d_ws);
}

// Round 7
// 5350.651 us; speedup vs baseline: 4.0102x; 4.0102x over previous
//
#include <hip/hip_runtime.h>
#include <cstddef>
#include <math.h>

// Problem: B=64, S=1024, F=128, H=512, V=64, T=64. f32 in/out.
// R13 = R8 (proven, 6396us, absmax 0.0) + surgical STAGE_H rewrite:
//  - R8's stage-write was an 8-way LDS bank conflict (16 lanes at 64B stride)
//    -> SQ_LDS_BANK_CONFLICT 1.87e8 (~10% of runtime), and its staging loads
//    were 16B/lane at 128B stride (4x line over-fetch on the far path).
//  - New mapping: load chunk u2 = u32 cols cq*4+u2*64 of row tid>>4 (per
//    instruction: 16 same-row lanes contiguous 256B, coalesced); LDS write
//    8B u32x2 at row*1024 + cq*8 + u2*128 ^ row-XOR (per instruction: each
//    row-group contiguous 128B across all 32 banks, conflict-free).
//  - EVERYTHING else byte-identical to R8: 4 groups x 16 batches, 32 WGs per
//    group h-sliced (16 dims/WG, 1 gate/wave), flag-based exchange on the
//    sc0|sc1 coherence-point path (the only protocol family that has been
//    bit-exact: R8/R9/R10 all absmax 0.0). XCD-L2 (sc0) exchange abandoned
//    after two run-varying failures (R11/R12).
#define NGROUP 4
#define WPG    32
#define NWG    128
#define BPG    16
#define BB  64
#define HH  512
#define TT  64
#define VV  64
#define FF  128
#define SS  1024

typedef _Float16 f16;
typedef _Float16 f16x8 __attribute__((ext_vector_type(8)));
typedef float    f32x4 __attribute__((ext_vector_type(4)));
typedef unsigned int u32;
typedef u32 u32x2 __attribute__((ext_vector_type(2)));
typedef u32 u32x4 __attribute__((ext_vector_type(4)));
typedef unsigned long long u64;

#define C1 4.8828125e-4f          // 2^-11
#define C2 2.384185791015625e-7f  // 2^-22

__device__ __forceinline__ void split8(const float* __restrict__ p, f16x8& hi, f16x8& lo) {
  f32x4 u = *(const f32x4*)p;
  f32x4 v = *(const f32x4*)(p + 4);
#pragma unroll
  for (int j = 0; j < 4; ++j) {
    f16 a = (f16)u[j]; hi[j]   = a; lo[j]   = (f16)((u[j] - (float)a) * 2048.0f);
    f16 b = (f16)v[j]; hi[4+j] = b; lo[4+j] = (f16)((v[j] - (float)b) * 2048.0f);
  }
}
__device__ __forceinline__ float sigmf_(float x) { return 1.0f / (1.0f + expf(-x)); }

// far (coherence-point) accessors — R4/R8-proven pattern
__device__ __forceinline__ f32x4 ld16f(const void* p) {
  f32x4 r;
  asm volatile("global_load_dwordx4 %0, %1, off sc0 sc1" : "=v"(r) : "v"(p) : "memory");
  return r;
}
__device__ __forceinline__ void st4f(u32* p, u32 v) {
  __hip_atomic_store(p, v, __ATOMIC_RELAXED, __HIP_MEMORY_SCOPE_AGENT);
}
__device__ __forceinline__ void st4ff(float* p, float v) {
  __hip_atomic_store(p, v, __ATOMIC_RELAXED, __HIP_MEMORY_SCOPE_AGENT);
}
__device__ __forceinline__ u32 ld4f(const u32* p) {
  return __hip_atomic_load(p, __ATOMIC_RELAXED, __HIP_MEMORY_SCOPE_AGENT);
}
#define VMWAIT asm volatile("s_waitcnt vmcnt(0)" ::: "memory")

// barrier: poll this group's 32 per-WG flags with one 64-lane gather
__device__ __forceinline__ void wait_flags(const u32* flags, u32 target, int lane) {
  const u32* a = flags + (size_t)(lane & 31) * 32;   // 128B stride
  while (!__all(ld4f(a) >= target))
    __builtin_amdgcn_s_sleep(1);
}

#define MFMA(d, a, b) d = __builtin_amdgcn_mfma_f32_16x16x32_f16(a, b, d, 0, 0, 0)

// one-shot h stage: group h tile [16][512] packed u32 -> LDS hi/lo f16.
// Thread (r=tid>>4, cq=tid&15): chunk u2 = u32 cols cq*4 + u2*64 of row r.
// Per load instruction: 16 same-row lanes contiguous 256B (coalesced).
// LDS write: 8B u32x2 at (r*1024 + cq*8 + u2*128) ^ ((r&7)<<4): per
// instruction each row-group is a contiguous 128B block -> conflict-free.
// rule #18: tie values through volatile asm + sched_barrier after VMWAIT.
#define STAGE_H(src_)                                                         \
  { const u32* src = (src_) + (size_t)(tid >> 4) * HH;                        \
    const int cq_ = tid & 15;                                                 \
    f32x4 sv[8];                                                              \
    _Pragma("unroll") for (int u2 = 0; u2 < 8; ++u2)                          \
      sv[u2] = ld16f(src + cq_*4 + u2*64);                                    \
    VMWAIT;                                                                   \
    _Pragma("unroll") for (int u2 = 0; u2 < 8; ++u2)                          \
      asm volatile("" : "+v"(sv[u2]));                                        \
    __builtin_amdgcn_sched_barrier(0);                                        \
    const int r_ = tid >> 4;                                                  \
    const size_t swz = (size_t)((r_ & 7) << 4);                               \
    _Pragma("unroll") for (int u2 = 0; u2 < 8; ++u2) {                        \
      union { f32x4 f; u32 u4[4]; } U; U.f = sv[u2];                          \
      u32 h0_ = (U.u4[0] & 0xffffu) | (U.u4[1] << 16);                        \
      u32 h1_ = (U.u4[2] & 0xffffu) | (U.u4[3] << 16);                        \
      u32 l0_ = (U.u4[0] >> 16) | (U.u4[1] & 0xffff0000u);                    \
      u32 l1_ = (U.u4[2] >> 16) | (U.u4[3] & 0xffff0000u);                    \
      size_t off = ((size_t)r_*1024 + (size_t)cq_*8 + (size_t)u2*128) ^ swz;  \
      *(u32x2*)((char*)sh_hi + off) = (u32x2){h0_, h1_};                      \
      *(u32x2*)((char*)sh_lo + off) = (u32x2){l0_, l1_};                      \
    } }                                                                       \
  __syncthreads();

// A-fragment read (row = batch mn, k-slice s), same swizzle as write side
#define LDA(s, ah, al)                                                        \
  { size_t o_ = ((size_t)mn * 1024 + (size_t)(s) * 64 + (size_t)(q8 * 2))     \
                ^ (size_t)((mn & 7) << 4);                                    \
    ah = *(const f16x8*)((const char*)sh_hi + o_);                            \
    al = *(const f16x8*)((const char*)sh_lo + o_); }

#define HPART()                                                               \
  _Pragma("unroll") for (int s = 0; s < 16; ++s) {                            \
    f16x8 ah, al; LDA(s, ah, al);                                             \
    MFMA(acc0, ah, whh_h[s]);                                                 \
    MFMA(acc1, al, whh_h[s]);                                                 \
    MFMA(acc1, ah, whh_l[s]);                                                 \
    MFMA(acc2, al, whh_l[s]);                                                 \
  }

// C/D layout: col = lane&15 = h-dim, row = (lane>>4)*4 + r = batch
#define GWRITE()                                                              \
  _Pragma("unroll") for (int r = 0; r < 4; ++r)                               \
    gate_buf[w][q * 4 + r][mn] = acc0[r] + C1 * acc1[r] + C2 * acc2[r];

__global__ void __launch_bounds__(256, 1) lstm_seq2seq(
    const float* __restrict__ sig,   // [B,S,F]
    const int*   __restrict__ tgt,   // [B,T]
    const float* __restrict__ eWih,  // [2048,128]
    const float* __restrict__ eWhh,  // [2048,512]
    const float* __restrict__ eBih,  // [2048]
    const float* __restrict__ eBhh,  // [2048]
    const float* __restrict__ dWih,  // [2048,64]
    const float* __restrict__ dWhh,  // [2048,512]
    const float* __restrict__ dBih,  // [2048]
    const float* __restrict__ dBhh,  // [2048]
    const float* __restrict__ oW,    // [64,512]
    const float* __restrict__ oB,    // [64]
    float*       __restrict__ out,   // [B,T,V]
    unsigned char* __restrict__ ws)
{
  // ws layout (bytes): [0,16384) flags 4 groups x 32 x 128B;
  // [16384,16640) idxbuf u32[64]; [20480,282624) h16 4 groups x 2 buf x 32KB
  // packed u32 {hi f16 | lo f16 << 16}; [282624,413696) hf32 4 groups x 32KB.
  // Zeroed region = [0,282624) every launch (ws re-poisoned 0xAA).
  const int wg = blockIdx.x;
  const int g  = wg >> 5;            // batch group
  const int p  = wg & 31;            // h-dim slice [p*16, p*16+16) per gate
  const int gb = g * BPG;            // global batch base
  u32* fl     = (u32*)ws + (size_t)g * 1024;
  u32* idxbuf = (u32*)(ws + 16384);
  u32* h16[2] = { (u32*)(ws + 20480) + (size_t)(g*2 + 0) * 8192,
                  (u32*)(ws + 20480) + (size_t)(g*2 + 1) * 8192 };
  float* hfg  = (float*)(ws + 282624) + (size_t)g * 8192;

  const int tid  = threadIdx.x;
  const int w    = tid >> 6;         // wave = gate (i,f,g,o)
  const int lane = tid & 63;
  const int q    = lane >> 4;
  const int mn   = lane & 15;
  const int q8   = q * 8;
  const int row  = w * HH + p * 16 + mn;  // weight row for this lane's B-frag
  const int cb   = tid >> 4;         // cell: local batch 0..15
  const int ck   = tid & 15;         // cell: dim within slice
  const int crow = p * 16 + ck;      // cell: h-dim

  __shared__ __attribute__((aligned(16))) f16 sh_hi[16 * 512]; // 16KB swizzled
  __shared__ __attribute__((aligned(16))) f16 sh_lo[16 * 512]; // single-buffered
  __shared__ float gate_buf[4][16][17];
  __shared__ float bias_buf[4][16];
  __shared__ __attribute__((aligned(16))) float hrow[512];
  __shared__ double psum[64];

  // ---- weights: W_hh and W_ih hi/lo fragments in registers ----
  f16x8 whh_h[16], whh_l[16], wih_h[4], wih_l[4];
#pragma unroll
  for (int s = 0; s < 16; ++s)
    split8(eWhh + (size_t)row * HH + s * 32 + q8, whh_h[s], whh_l[s]);
#pragma unroll
  for (int s = 0; s < 4; ++s)
    split8(eWih + (size_t)row * FF + s * 32 + q8, wih_h[s], wih_l[s]);
  if (tid < 64) {
    int g4 = tid >> 4, kl = tid & 15;
    int r = g4 * HH + p * 16 + kl;
    bias_buf[g4][kl] = eBih[r] + eBhh[r];
  }
  if (p == 0 && tid < BPG)
    st4f(idxbuf + gb + tid, (u32)tgt[(size_t)(gb + tid) * TT]);  // target[:,0]
  __syncthreads();

  float c_reg = 0.f;
  int cur = 0;                       // h dbuf (zeroed by memset = h0)
  const f32x4 zero4 = {0.f, 0.f, 0.f, 0.f};

  // ================= encoder: 1024 steps =================
  for (int t = 0; t < SS; ++t) {
    f32x4 acc0 = zero4, acc1 = zero4, acc2 = zero4;
    // x-part: h-independent, overlaps other WGs finishing step t-1
    const float* sb = sig + (size_t)(gb + mn) * (SS * FF) + (size_t)t * FF;
#pragma unroll
    for (int s = 0; s < 4; ++s) {
      f16x8 ah, al;
      split8(sb + s * 32 + q8, ah, al);
      MFMA(acc0, ah, wih_h[s]);
      MFMA(acc1, al, wih_h[s]);
      MFMA(acc1, ah, wih_l[s]);
      MFMA(acc2, al, wih_l[s]);
    }
    wait_flags(fl, (u32)t, lane);
    STAGE_H(h16[cur])
    HPART()
    GWRITE()
    __syncthreads();
    // LSTM cell: 1 h-value per thread (f32, precise libm)
    {
      float gi = gate_buf[0][cb][ck] + bias_buf[0][ck];
      float gf = gate_buf[1][cb][ck] + bias_buf[1][ck];
      float gg = gate_buf[2][cb][ck] + bias_buf[2][ck];
      float go = gate_buf[3][cb][ck] + bias_buf[3][ck];
      float c  = sigmf_(gf) * c_reg + sigmf_(gi) * tanhf(gg);
      float h  = sigmf_(go) * tanhf(c);
      c_reg = c;
      f16 hh = (f16)h;
      f16 hl = (f16)((h - (float)hh) * 2048.0f);
      union { f16 h2[2]; u32 u; } pk;
      pk.h2[0] = hh; pk.h2[1] = hl;
      st4f(h16[cur ^ 1] + (size_t)cb * HH + crow, pk.u);
    }
    VMWAIT;             // h store acked at coherence point
    __syncthreads();
    if (tid == 0) st4f(fl + p * 32, (u32)(t + 1));
    cur ^= 1;
  }

  // ================= decoder setup =================
#pragma unroll
  for (int s = 0; s < 16; ++s)
    split8(dWhh + (size_t)row * HH + s * 32 + q8, whh_h[s], whh_l[s]);
  __syncthreads();
  if (tid < 64) {
    int g4 = tid >> 4, kl = tid & 15;
    int r = g4 * HH + p * 16 + kl;
    bias_buf[g4][kl] = dBih[r] + dBhh[r];
  }
  __syncthreads();

  // ================= decoder: 64 steps =================
  for (int t = 0; t < TT; ++t) {
    // ---- phase A: cell. x = one_hot(idx) -> column gather at cell stage ----
    wait_flags(fl, (u32)(SS + 2 * t), lane);
    f32x4 acc0 = zero4, acc1 = zero4, acc2 = zero4;
    STAGE_H(h16[cur])
    HPART()
    GWRITE()
    __syncthreads();
    {
      int ib = (int)ld4f(idxbuf + gb + cb);
      float gi = gate_buf[0][cb][ck] + bias_buf[0][ck] + dWih[(size_t)(0*HH + crow) * VV + ib];
      float gf = gate_buf[1][cb][ck] + bias_buf[1][ck] + dWih[(size_t)(1*HH + crow) * VV + ib];
      float gg = gate_buf[2][cb][ck] + bias_buf[2][ck] + dWih[(size_t)(2*HH + crow) * VV + ib];
      float go = gate_buf[3][cb][ck] + bias_buf[3][ck] + dWih[(size_t)(3*HH + crow) * VV + ib];
      float c  = sigmf_(gf) * c_reg + sigmf_(gi) * tanhf(gg);
      float h  = sigmf_(go) * tanhf(c);
      c_reg = c;
      f16 hh = (f16)h;
      f16 hl = (f16)((h - (float)hh) * 2048.0f);
      union { f16 h2[2]; u32 u; } pk;
      pk.h2[0] = hh; pk.h2[1] = hl;
      st4f(h16[cur ^ 1] + (size_t)cb * HH + crow, pk.u);
      st4ff(hfg + (size_t)cb * HH + crow, h);
    }
    VMWAIT;
    __syncthreads();
    if (tid == 0) st4f(fl + p * 32, (u32)(SS + 2 * t + 1));
    int nxt = cur ^ 1;

    // ---- phase B: f64 logits + log_softmax + argmax (WG p<16 = batch p) ----
    wait_flags(fl, (u32)(SS + 2 * t + 1), lane);
    if (p < BPG) {
      if (tid < 128) {
        f32x4 hv = ld16f(hfg + (size_t)p * HH + tid * 4);
        VMWAIT;
        *(f32x4*)&hrow[tid * 4] = hv;
      }
      __syncthreads();
      double acc = 0.0;
      if (w < 2) {                   // waves 0,1 split K=512 in halves
        const float* wr = oW + (size_t)lane * HH + w * 256;
        const float* hr = hrow + w * 256;
#pragma unroll 4
        for (int kc = 0; kc < 64; ++kc) {
          f32x4 hv = *(const f32x4*)(hr + kc * 4);
          f32x4 wv = *(const f32x4*)(wr + kc * 4);
          acc += (double)hv[0]*(double)wv[0] + (double)hv[1]*(double)wv[1]
               + (double)hv[2]*(double)wv[2] + (double)hv[3]*(double)wv[3];
        }
        if (w == 1) psum[lane] = acc;
      }
      __syncthreads();
      if (w == 0) {
        double l = acc + psum[lane] + (double)oB[lane];
        double mx = l; int ai = lane;
#pragma unroll
        for (int o = 32; o > 0; o >>= 1) {
          double om = __shfl_xor(mx, o, 64);
          int    oi = __shfl_xor(ai, o, 64);
          if (om > mx || (om == mx && oi < ai)) { mx = om; ai = oi; }
        }
        double se = exp(l - mx);
#pragma unroll
        for (int o = 32; o > 0; o >>= 1) se += __shfl_xor(se, o, 64);
        double lse = mx + log(se);
        out[((size_t)(gb + p) * TT + t) * VV + lane] = (float)(l - lse);
        if (lane == 0) st4f(idxbuf + gb + p, (u32)ai);
      }
    }
    VMWAIT;
    __syncthreads();
    if (tid == 0) st4f(fl + p * 32, (u32)(SS + 2 * t + 2));
    cur = nxt;
  }
}

extern "C" void kernel_launch(void* const* d_in, const int* in_sizes, int n_in,
                              void* d_out, int out_size, void* d_ws, size_t ws_size,
                              hipStream_t stream) {
  (void)in_sizes; (void)n_in; (void)out_size; (void)ws_size;
  // zero: flags + idxbuf + h16 dbufs (ws re-poisoned 0xAA before every timed
  // launch -> must zero every call). hf32 fully written before read.
  hipMemsetAsync(d_ws, 0, 282624, stream);
  lstm_seq2seq<<<dim3(NWG), dim3(256), 0, stream>>>(
      (const float*)d_in[0],  (const int*)d_in[1],
      (const float*)d_in[2],  (const float*)d_in[3],
      (const float*)d_in[4],  (const float*)d_in[5],
      (const float*)d_in[6],  (const float*)d_in[7],
      (const float*)d_in[8],  (const float*)d_in[9],
      (const float*)d_in[10], (const float*)d_in[11],
      (float*)d_out, (unsigned char*)d_ws);
}

// Round 8
// 5015.538 us; speedup vs baseline: 4.2782x; 1.0668x over previous
//
#include <hip/hip_runtime.h>
#include <cstddef>
#include <math.h>

// Problem: B=64, S=1024, F=128, H=512, V=64, T=64. f32 in/out.
// R14 = R13 (proven 5351us, absmax 0.0) + two surgical changes:
//  (1) h exchanged f16-only (W_hh/W_ih keep full Ootomo hi+lo; x keeps full
//      split). Far staged volume halves (32KB->16KB/group/step, 256K->128K
//      16B sc1 transactions/step), HPART 64->32 MFMA, stage unpack VALU gone
//      (loaded u32 = packed f16 pair, written straight to LDS). c_reg stays
//      f32; phase-B logits read f32 h. Error budget ~6e-3 << 0.09 threshold.
//  (2) store-ack hidden: x-part(t+1) computed BETWEEN h-store issue and its
//      VMWAIT (software pipeline); h pair-packed via __shfl_xor (no extra
//      barrier; 3 barriers/step unchanged).
//  Everything else identical to R13: 4 groups x 16 batches, 32 WGs/group
//  h-sliced (16 dims/WG, 1 gate/wave), flag exchange on the sc0|sc1
//  coherence-point path (only protocol family that has been bit-exact).
#define NGROUP 4
#define WPG    32
#define NWG    128
#define BPG    16
#define BB  64
#define HH  512
#define TT  64
#define VV  64
#define FF  128
#define SS  1024

typedef _Float16 f16;
typedef _Float16 f16x8 __attribute__((ext_vector_type(8)));
typedef float    f32x4 __attribute__((ext_vector_type(4)));
typedef unsigned int u32;
typedef u32 u32x4 __attribute__((ext_vector_type(4)));
typedef unsigned long long u64;

#define C1 4.8828125e-4f          // 2^-11
#define C2 2.384185791015625e-7f  // 2^-22

__device__ __forceinline__ void split8(const float* __restrict__ p, f16x8& hi, f16x8& lo) {
  f32x4 u = *(const f32x4*)p;
  f32x4 v = *(const f32x4*)(p + 4);
#pragma unroll
  for (int j = 0; j < 4; ++j) {
    f16 a = (f16)u[j]; hi[j]   = a; lo[j]   = (f16)((u[j] - (float)a) * 2048.0f);
    f16 b = (f16)v[j]; hi[4+j] = b; lo[4+j] = (f16)((v[j] - (float)b) * 2048.0f);
  }
}
__device__ __forceinline__ float sigmf_(float x) { return 1.0f / (1.0f + expf(-x)); }

// far (coherence-point) accessors — R4/R8/R13-proven pattern
__device__ __forceinline__ f32x4 ld16f(const void* p) {
  f32x4 r;
  asm volatile("global_load_dwordx4 %0, %1, off sc0 sc1" : "=v"(r) : "v"(p) : "memory");
  return r;
}
__device__ __forceinline__ void st4f(u32* p, u32 v) {
  __hip_atomic_store(p, v, __ATOMIC_RELAXED, __HIP_MEMORY_SCOPE_AGENT);
}
__device__ __forceinline__ void st4ff(float* p, float v) {
  __hip_atomic_store(p, v, __ATOMIC_RELAXED, __HIP_MEMORY_SCOPE_AGENT);
}
__device__ __forceinline__ u32 ld4f(const u32* p) {
  return __hip_atomic_load(p, __ATOMIC_RELAXED, __HIP_MEMORY_SCOPE_AGENT);
}
#define VMWAIT asm volatile("s_waitcnt vmcnt(0)" ::: "memory")

// barrier: poll this group's 32 per-WG flags with one 64-lane gather
__device__ __forceinline__ void wait_flags(const u32* flags, u32 target, int lane) {
  const u32* a = flags + (size_t)(lane & 31) * 32;   // 128B stride
  while (!__all(ld4f(a) >= target))
    __builtin_amdgcn_s_sleep(1);
}

#define MFMA(d, a, b) d = __builtin_amdgcn_mfma_f32_16x16x32_f16(a, b, d, 0, 0, 0)

// one-shot h stage: group tile [16][256] u32 (f16 dim pairs) -> LDS f16.
// Thread (r=tid>>4, cq=tid&15), chunk u2: u32 cols cq*4+u2*64 of row r.
// Per instruction: 16 same-row lanes contiguous 256B (coalesced far reads);
// LDS write u32x4 at (r*1024 + cq*16 + u2*256) ^ ((r&7)<<4): each 16-lane
// row-group covers two full bank windows, 8 lanes/window -> conflict-free.
// rule #18: tie values through volatile asm + sched_barrier after VMWAIT.
#define STAGE_H(src_)                                                         \
  { const u32* src = (src_) + (size_t)(tid >> 4) * 256;                       \
    const int cq_ = tid & 15;                                                 \
    f32x4 sv[4];                                                              \
    _Pragma("unroll") for (int u2 = 0; u2 < 4; ++u2)                          \
      sv[u2] = ld16f(src + cq_*4 + u2*64);                                    \
    VMWAIT;                                                                   \
    _Pragma("unroll") for (int u2 = 0; u2 < 4; ++u2)                          \
      asm volatile("" : "+v"(sv[u2]));                                        \
    __builtin_amdgcn_sched_barrier(0);                                        \
    const int r_ = tid >> 4;                                                  \
    const size_t swz = (size_t)((r_ & 7) << 4);                               \
    _Pragma("unroll") for (int u2 = 0; u2 < 4; ++u2) {                        \
      size_t off = ((size_t)r_*1024 + (size_t)cq_*16 + (size_t)u2*256) ^ swz; \
      *(u32x4*)((char*)sh_h + off) = __builtin_bit_cast(u32x4, sv[u2]);       \
    } }                                                                       \
  __syncthreads();

// A-fragment read (row = batch mn, k-slice s), same swizzle as write side
#define LDA(s, ah)                                                            \
  { size_t o_ = ((size_t)mn * 1024 + (size_t)(s) * 64 + (size_t)(q8 * 2))     \
                ^ (size_t)((mn & 7) << 4);                                    \
    ah = *(const f16x8*)((const char*)sh_h + o_); }

// h-part: h f16-only; W hi+lo -> gates pick up C1-scaled W-lo correction.
#define HPART()                                                               \
  _Pragma("unroll") for (int s = 0; s < 16; ++s) {                            \
    f16x8 ah; LDA(s, ah);                                                     \
    MFMA(acc0, ah, whh_h[s]);                                                 \
    MFMA(acc1, ah, whh_l[s]);                                                 \
  }

// x-part for sig row ts (full Ootomo), (re)initializes acc0..2
#define XPART(ts)                                                             \
  { acc0 = zero4; acc1 = zero4; acc2 = zero4;                                 \
    const float* sb = sig + (size_t)(gb + mn) * (SS * FF) + (size_t)(ts) * FF;\
    _Pragma("unroll") for (int s = 0; s < 4; ++s) {                           \
      f16x8 xh, xl;                                                           \
      split8(sb + s * 32 + q8, xh, xl);                                       \
      MFMA(acc0, xh, wih_h[s]);                                               \
      MFMA(acc1, xl, wih_h[s]);                                               \
      MFMA(acc1, xh, wih_l[s]);                                               \
      MFMA(acc2, xl, wih_l[s]);                                               \
    } }

// C/D layout: col = lane&15 = h-dim, row = (lane>>4)*4 + r = batch
#define GWRITE()                                                              \
  _Pragma("unroll") for (int r = 0; r < 4; ++r)                               \
    gate_buf[w][q * 4 + r][mn] = acc0[r] + C1 * acc1[r] + C2 * acc2[r];

// pack h f16 pair across (even,odd) lanes via shfl; even tids store u32.
// h16 row = 256 u32: col = dim/2 = p*8 + ck/2.
#define HSTORE(dst)                                                           \
  { f16 hh = (f16)h;                                                          \
    u32 mine = (u32)__builtin_bit_cast(unsigned short, hh);                   \
    u32 part = (u32)__shfl_xor((int)mine, 1, 64);                             \
    if ((tid & 1) == 0)                                                       \
      st4f((dst) + (size_t)cb * 256 + p * 8 + (ck >> 1), mine | (part << 16)); }

__global__ void __launch_bounds__(256, 1) lstm_seq2seq(
    const float* __restrict__ sig,   // [B,S,F]
    const int*   __restrict__ tgt,   // [B,T]
    const float* __restrict__ eWih,  // [2048,128]
    const float* __restrict__ eWhh,  // [2048,512]
    const float* __restrict__ eBih,  // [2048]
    const float* __restrict__ eBhh,  // [2048]
    const float* __restrict__ dWih,  // [2048,64]
    const float* __restrict__ dWhh,  // [2048,512]
    const float* __restrict__ dBih,  // [2048]
    const float* __restrict__ dBhh,  // [2048]
    const float* __restrict__ oW,    // [64,512]
    const float* __restrict__ oB,    // [64]
    float*       __restrict__ out,   // [B,T,V]
    unsigned char* __restrict__ ws)
{
  // ws layout (bytes): [0,16384) flags 4 groups x 32 x 128B;
  // [16384,16640) idxbuf u32[64]; [20480,151552) h16 4 groups x 2 buf x 16KB
  // u32 {f16 dim2j | f16 dim2j+1 <<16}; [151552,282624) hf32 4 groups x 32KB.
  // Zeroed region = [0,151552) every launch (ws re-poisoned 0xAA); packed 0
  // = h0 = zeros. hf32 fully written before read (flag-guarded).
  const int wg = blockIdx.x;
  const int g  = wg >> 5;            // batch group
  const int p  = wg & 31;            // h-dim slice [p*16, p*16+16) per gate
  const int gb = g * BPG;            // global batch base
  u32* fl     = (u32*)ws + (size_t)g * 1024;
  u32* idxbuf = (u32*)(ws + 16384);
  u32* h16[2] = { (u32*)(ws + 20480) + (size_t)(g*2 + 0) * 4096,
                  (u32*)(ws + 20480) + (size_t)(g*2 + 1) * 4096 };
  float* hfg  = (float*)(ws + 151552) + (size_t)g * 8192;

  const int tid  = threadIdx.x;
  const int w    = tid >> 6;         // wave = gate (i,f,g,o)
  const int lane = tid & 63;
  const int q    = lane >> 4;
  const int mn   = lane & 15;
  const int q8   = q * 8;
  const int row  = w * HH + p * 16 + mn;  // weight row for this lane's B-frag
  const int cb   = tid >> 4;         // cell: local batch 0..15
  const int ck   = tid & 15;         // cell: dim within slice
  const int crow = p * 16 + ck;      // cell: h-dim

  __shared__ __attribute__((aligned(16))) f16 sh_h[16 * 512]; // 16KB swizzled
  __shared__ float gate_buf[4][16][17];
  __shared__ float bias_buf[4][16];
  __shared__ __attribute__((aligned(16))) float hrow[512];
  __shared__ double psum[64];

  // ---- weights: W_hh and W_ih hi/lo fragments in registers ----
  f16x8 whh_h[16], whh_l[16], wih_h[4], wih_l[4];
#pragma unroll
  for (int s = 0; s < 16; ++s)
    split8(eWhh + (size_t)row * HH + s * 32 + q8, whh_h[s], whh_l[s]);
#pragma unroll
  for (int s = 0; s < 4; ++s)
    split8(eWih + (size_t)row * FF + s * 32 + q8, wih_h[s], wih_l[s]);
  if (tid < 64) {
    int g4 = tid >> 4, kl = tid & 15;
    int r = g4 * HH + p * 16 + kl;
    bias_buf[g4][kl] = eBih[r] + eBhh[r];
  }
  if (p == 0 && tid < BPG)
    st4f(idxbuf + gb + tid, (u32)tgt[(size_t)(gb + tid) * TT]);  // target[:,0]
  __syncthreads();

  float c_reg = 0.f;
  int cur = 0;                       // h dbuf (zeroed by memset = h0)
  const f32x4 zero4 = {0.f, 0.f, 0.f, 0.f};
  f32x4 acc0, acc1, acc2;

  // ================= encoder: 1024 steps (x-part pipelined) =================
  XPART(0)
  for (int t = 0; t < SS; ++t) {
    wait_flags(fl, (u32)t, lane);
    STAGE_H(h16[cur])
    HPART()
    GWRITE()
    __syncthreads();
    // LSTM cell: 1 h-value per thread (f32, precise libm)
    {
      float gi = gate_buf[0][cb][ck] + bias_buf[0][ck];
      float gf = gate_buf[1][cb][ck] + bias_buf[1][ck];
      float gg = gate_buf[2][cb][ck] + bias_buf[2][ck];
      float go = gate_buf[3][cb][ck] + bias_buf[3][ck];
      float c  = sigmf_(gf) * c_reg + sigmf_(gi) * tanhf(gg);
      float h  = sigmf_(go) * tanhf(c);
      c_reg = c;
      HSTORE(h16[cur ^ 1])
    }
    // x-part(t+1) overlaps the h-store ack (clamped: t=SS-1 result unused)
    XPART(t + 1 < SS ? t + 1 : SS - 1)
    VMWAIT;             // h store acked at coherence point (+ sig drained)
    __syncthreads();
    if (tid == 0) st4f(fl + p * 32, (u32)(t + 1));
    cur ^= 1;
  }

  // ================= decoder setup =================
#pragma unroll
  for (int s = 0; s < 16; ++s)
    split8(dWhh + (size_t)row * HH + s * 32 + q8, whh_h[s], whh_l[s]);
  __syncthreads();
  if (tid < 64) {
    int g4 = tid >> 4, kl = tid & 15;
    int r = g4 * HH + p * 16 + kl;
    bias_buf[g4][kl] = dBih[r] + dBhh[r];
  }
  __syncthreads();

  // ================= decoder: 64 steps =================
  for (int t = 0; t < TT; ++t) {
    // ---- phase A: cell. x = one_hot(idx) -> column gather at cell stage ----
    wait_flags(fl, (u32)(SS + 2 * t), lane);
    acc0 = zero4; acc1 = zero4; acc2 = zero4;
    STAGE_H(h16[cur])
    HPART()
    GWRITE()
    __syncthreads();
    {
      int ib = (int)ld4f(idxbuf + gb + cb);
      float gi = gate_buf[0][cb][ck] + bias_buf[0][ck] + dWih[(size_t)(0*HH + crow) * VV + ib];
      float gf = gate_buf[1][cb][ck] + bias_buf[1][ck] + dWih[(size_t)(1*HH + crow) * VV + ib];
      float gg = gate_buf[2][cb][ck] + bias_buf[2][ck] + dWih[(size_t)(2*HH + crow) * VV + ib];
      float go = gate_buf[3][cb][ck] + bias_buf[3][ck] + dWih[(size_t)(3*HH + crow) * VV + ib];
      float c  = sigmf_(gf) * c_reg + sigmf_(gi) * tanhf(gg);
      float h  = sigmf_(go) * tanhf(c);
      c_reg = c;
      HSTORE(h16[cur ^ 1])
      st4ff(hfg + (size_t)cb * HH + crow, h);
    }
    VMWAIT;
    __syncthreads();
    if (tid == 0) st4f(fl + p * 32, (u32)(SS + 2 * t + 1));
    int nxt = cur ^ 1;

    // ---- phase B: f64 logits + log_softmax + argmax (WG p<16 = batch p) ----
    wait_flags(fl, (u32)(SS + 2 * t + 1), lane);
    if (p < BPG) {
      if (tid < 128) {
        f32x4 hv = ld16f(hfg + (size_t)p * HH + tid * 4);
        VMWAIT;
        *(f32x4*)&hrow[tid * 4] = hv;
      }
      __syncthreads();
      double acc = 0.0;
      if (w < 2) {                   // waves 0,1 split K=512 in halves
        const float* wr = oW + (size_t)lane * HH + w * 256;
        const float* hr = hrow + w * 256;
#pragma unroll 4
        for (int kc = 0; kc < 64; ++kc) {
          f32x4 hv = *(const f32x4*)(hr + kc * 4);
          f32x4 wv = *(const f32x4*)(wr + kc * 4);
          acc += (double)hv[0]*(double)wv[0] + (double)hv[1]*(double)wv[1]
               + (double)hv[2]*(double)wv[2] + (double)hv[3]*(double)wv[3];
        }
        if (w == 1) psum[lane] = acc;
      }
      __syncthreads();
      if (w == 0) {
        double l = acc + psum[lane] + (double)oB[lane];
        double mx = l; int ai = lane;
#pragma unroll
        for (int o = 32; o > 0; o >>= 1) {
          double om = __shfl_xor(mx, o, 64);
          int    oi = __shfl_xor(ai, o, 64);
          if (om > mx || (om == mx && oi < ai)) { mx = om; ai = oi; }
        }
        double se = exp(l - mx);
#pragma unroll
        for (int o = 32; o > 0; o >>= 1) se += __shfl_xor(se, o, 64);
        double lse = mx + log(se);
        out[((size_t)(gb + p) * TT + t) * VV + lane] = (float)(l - lse);
        if (lane == 0) st4f(idxbuf + gb + p, (u32)ai);
      }
    }
    VMWAIT;
    __syncthreads();
    if (tid == 0) st4f(fl + p * 32, (u32)(SS + 2 * t + 2));
    cur = nxt;
  }
}

extern "C" void kernel_launch(void* const* d_in, const int* in_sizes, int n_in,
                              void* d_out, int out_size, void* d_ws, size_t ws_size,
                              hipStream_t stream) {
  (void)in_sizes; (void)n_in; (void)out_size; (void)ws_size;
  // zero: flags + idxbuf + h16 dbufs (ws re-poisoned 0xAA before every timed
  // launch -> must zero every call). hf32 fully written before read.
  hipMemsetAsync(d_ws, 0, 151552, stream);
  lstm_seq2seq<<<dim3(NWG), dim3(256), 0, stream>>>(
      (const float*)d_in[0],  (const int*)d_in[1],
      (const float*)d_in[2],  (const float*)d_in[3],
      (const float*)d_in[4],  (const float*)d_in[5],
      (const float*)d_in[6],  (const float*)d_in[7],
      (const float*)d_in[8],  (const float*)d_in[9],
      (const float*)d_in[10], (const float*)d_in[11],
      (float*)d_out, (unsigned char*)d_ws);
}